// Round 5
// baseline (64.414 us; speedup 1.0000x reference)
//
#include <hip/hip_runtime.h>
#include <math.h>

#define IMG_H 2048
#define IMG_W 2048
#define NIMG 8

typedef float f32x4 __attribute__((ext_vector_type(4)));

// fast sigmoid: v_exp_f32 + raw v_rcp_f32, ~1e-7 rel error. Only used away
// from the decision boundary (guard band 1e-4); borderline pixels fall
// through to the exact np-f32-pipeline emulation.
__device__ __forceinline__ float fast_sigmoid(float v) {
    float e = __builtin_amdgcn_exp2f(v * -1.44269504088896341f); // exp(-v)
    return __builtin_amdgcn_rcpf(1.0f + e);                      // ~1 ulp rcp
}

// Emulate numpy float32 pipeline: 1.0f / (1.0f + exp_f32(-x)) with a
// correctly-rounded f32 exp (via double), keeping both f32 roundings.
__device__ __forceinline__ float np_sigmoid_f32(float v) {
    float e = (float)exp(-(double)v);   // CR float32 exp
    float d = 1.0f + e;                 // f32 add
    return 1.0f / d;                    // f32 CR div
}

// Each thread: 8 output cols (2x float4) x 4 output rows.
// Block: 64 x 4 threads -> tile of 512 cols x 16 rows.
__global__ __launch_bounds__(256) void morph_grad_kernel(
    const float* __restrict__ in, float* __restrict__ out)
{
    const int tx   = threadIdx.x;                  // 0..63
    const int ty   = threadIdx.y;                  // 0..3
    const int c    = blockIdx.x * 512 + tx * 8;    // col base (mult of 8)
    const int row0 = blockIdx.y * 16 + ty * 4;     // output row base
    const int img  = blockIdx.z;

    const float* base = in + (size_t)img * (size_t)(IMG_H * IMG_W);

    const bool hasL = (c != 0);           // only (bx==0, tx==0) lacks left halo
    const bool hasR = (c != IMG_W - 8);   // only (bx==3, tx==63) lacks right halo

    // accumulators for 4 output rows x 8 cols (first fold is an assignment)
    float accM[4][8], accm[4][8];

    #pragma unroll
    for (int r = 0; r < 8; ++r) {
        int y = row0 - 2 + r;
        y = y < 0 ? 0 : (y > IMG_H - 1 ? IMG_H - 1 : y);   // clamp == geodesic
        const float* rp = base + (size_t)y * IMG_W;

        float4 A = *reinterpret_cast<const float4*>(rp + c);      // 32B-aligned pair
        float4 B = *reinterpret_cast<const float4*>(rp + c + 4);
        float2 L, R;
        if (hasL) L = *reinterpret_cast<const float2*>(rp + c - 2);
        else      L = make_float2(A.x, A.x);                      // clamp col
        if (hasR) R = *reinterpret_cast<const float2*>(rp + c + 8);
        else      R = make_float2(B.w, B.w);                      // clamp col

        float w[12] = {L.x, L.y, A.x, A.y, A.z, A.w, B.x, B.y, B.z, B.w, R.x, R.y};

        // sliding width-5 max/min via pairwise tree: 3.5 ops/output
        float pM[11], pm[11];
        #pragma unroll
        for (int i = 0; i < 11; ++i) { pM[i] = fmaxf(w[i], w[i+1]); pm[i] = fminf(w[i], w[i+1]); }
        float hM[8], hm[8];
        #pragma unroll
        for (int j = 0; j < 8; ++j) {
            float qM = fmaxf(pM[j], pM[j+2]);     // max of w[j..j+3]
            float qm = fminf(pm[j], pm[j+2]);
            hM[j] = fmaxf(qM, w[j+4]);
            hm[j] = fminf(qm, w[j+4]);
        }

        // fold into affected output rows (r,k compile-time -> branches vanish)
        #pragma unroll
        for (int k = 0; k < 4; ++k) {
            if (r == k) {                       // first contributor: center col, row yo-2
                #pragma unroll
                for (int j = 0; j < 8; ++j) { accM[k][j] = w[j+2]; accm[k][j] = w[j+2]; }
            } else if (r == k + 1 || r == k + 2 || r == k + 3) {  // full 5-wide rows
                #pragma unroll
                for (int j = 0; j < 8; ++j) {
                    accM[k][j] = fmaxf(accM[k][j], hM[j]);
                    accm[k][j] = fminf(accm[k][j], hm[j]);
                }
            } else if (r == k + 4) {            // center col, row yo+2
                #pragma unroll
                for (int j = 0; j < 8; ++j) {
                    accM[k][j] = fmaxf(accM[k][j], w[j+2]);
                    accm[k][j] = fminf(accm[k][j], w[j+2]);
                }
            }
        }
    }

    float* obase = out + (size_t)img * (size_t)(IMG_H * IMG_W);

    #pragma unroll
    for (int k = 0; k < 4; ++k) {
        float res[8];
        bool border = false;
        #pragma unroll
        for (int j = 0; j < 8; ++j) {
            float g = fast_sigmoid(accM[k][j]) - fast_sigmoid(accm[k][j]);
            res[j] = (g > 0.5f) ? 1.0f : 0.0f;
            border |= (fabsf(g - 0.5f) < 1e-4f);
        }
        if (__builtin_expect(border, 0)) {
            // exact np-f32 pipeline; safe to redo all 8 (fast/exact can only
            // disagree inside the guard band)
            #pragma unroll
            for (int j = 0; j < 8; ++j) {
                float sM = np_sigmoid_f32(accM[k][j]);
                float sm = np_sigmoid_f32(accm[k][j]);
                res[j] = ((sM - sm) > 0.5f) ? 1.0f : 0.0f;
            }
        }
        float* op = obase + (size_t)(row0 + k) * IMG_W + c;   // 32B aligned
        f32x4 o0 = {res[0], res[1], res[2], res[3]};
        f32x4 o1 = {res[4], res[5], res[6], res[7]};
        // output is never re-read: stream past L2 to keep it for input halos
        __builtin_nontemporal_store(o0, reinterpret_cast<f32x4*>(op));
        __builtin_nontemporal_store(o1, reinterpret_cast<f32x4*>(op) + 1);
    }
}

extern "C" void kernel_launch(void* const* d_in, const int* in_sizes, int n_in,
                              void* d_out, int out_size, void* d_ws, size_t ws_size,
                              hipStream_t stream) {
    const float* x = (const float*)d_in[0];
    float* out = (float*)d_out;
    dim3 grid(IMG_W / 512, IMG_H / 16, NIMG);   // 4 x 128 x 8 = 4096 blocks
    dim3 block(64, 4, 1);
    hipLaunchKernelGGL(morph_grad_kernel, grid, block, 0, stream, x, out);
}

// Round 6
// 59.858 us; speedup vs baseline: 1.0761x; 1.0761x over previous
//
#include <hip/hip_runtime.h>
#include <math.h>

#define IMG_H 2048
#define IMG_W 2048
#define NIMG 8
#define RPT   16              // output rows per thread
#define STEPS (RPT + 4)       // loaded rows per thread (±2 halo)

// fast sigmoid: v_exp_f32 + raw v_rcp_f32, ~1e-7 rel error. Only used away
// from the decision boundary (guard band 1e-4); borderline pixels fall
// through to the exact np-f32-pipeline emulation.
__device__ __forceinline__ float fast_sigmoid(float v) {
    float e = __builtin_amdgcn_exp2f(v * -1.44269504088896341f); // exp(-v)
    return __builtin_amdgcn_rcpf(1.0f + e);                      // ~1 ulp rcp
}

// Emulate numpy float32 pipeline: 1.0f / (1.0f + exp_f32(-x)) with a
// correctly-rounded f32 exp (via double), keeping both f32 roundings.
__device__ __forceinline__ float np_sigmoid_f32(float v) {
    float e = (float)exp(-(double)v);   // CR float32 exp
    float d = 1.0f + e;                 // f32 add
    return 1.0f / d;                    // f32 CR div
}

// Rolling-window column strip: each thread owns 4 cols x 16 rows, walks 20
// row-steps; horizontal 5-window max/min computed ONCE per loaded row
// (1.25 row-loads per output row vs 2.0 in the tile version). All array
// indices are compile-time after full unroll -> pure register ring.
// Block: 64x4 threads -> 256 cols x 64 rows per block. 2048 blocks.
__global__ __launch_bounds__(256) void morph_grad_kernel(
    const float* __restrict__ in, float* __restrict__ out)
{
    const int tx  = threadIdx.x;                        // 0..63
    const int ty  = threadIdx.y;                        // 0..3
    const int c   = blockIdx.x * 256 + tx * 4;          // col base (mult of 4)
    const int y0  = (blockIdx.y * 4 + ty) * RPT;        // first output row
    const int img = blockIdx.z;

    const float* base  = in  + (size_t)img * (size_t)(IMG_H * IMG_W);
    float*       obase = out + (size_t)img * (size_t)(IMG_H * IMG_W);

    const bool hasL = (c != 0);          // image-edge columns
    const bool hasR = (c != IMG_W - 4);

    // per-step horizontal results; live range is 5 steps -> register ring
    float hM[STEPS][4], hm[STEPS][4], cc[STEPS][4];

    #pragma unroll
    for (int s = 0; s < STEPS; ++s) {
        int y = y0 - 2 + s;
        y = y < 0 ? 0 : (y > IMG_H - 1 ? IMG_H - 1 : y);   // clamp == geodesic
        const float* rp = base + (size_t)y * IMG_W;

        float4 A = *reinterpret_cast<const float4*>(rp + c);        // 16B aligned
        float2 L, R;
        if (hasL) L = *reinterpret_cast<const float2*>(rp + c - 2); // 8B aligned
        else      L = make_float2(A.x, A.x);                        // clamp col
        if (hasR) R = *reinterpret_cast<const float2*>(rp + c + 4); // 16B aligned
        else      R = make_float2(A.w, A.w);                        // clamp col

        float w[8] = {L.x, L.y, A.x, A.y, A.z, A.w, R.x, R.y};

        // sliding width-5 max/min via pairwise tree
        float pM[7], pm[7];
        #pragma unroll
        for (int i = 0; i < 7; ++i) {
            pM[i] = fmaxf(w[i], w[i + 1]);
            pm[i] = fminf(w[i], w[i + 1]);
        }
        #pragma unroll
        for (int j = 0; j < 4; ++j) {
            hM[s][j] = fmaxf(fmaxf(pM[j], pM[j + 2]), w[j + 4]);
            hm[s][j] = fminf(fminf(pm[j], pm[j + 2]), w[j + 4]);
            cc[s][j] = w[j + 2];
        }

        // emit output row yo = y0 + s - 4 once its full window is loaded
        if (s >= 4) {
            const int yo = y0 + s - 4;
            float Mv[4], mv[4], res[4];
            bool border = false;
            #pragma unroll
            for (int j = 0; j < 4; ++j) {
                float a = fmaxf(fmaxf(hM[s-3][j], hM[s-2][j]), hM[s-1][j]);
                Mv[j] = fmaxf(a, fmaxf(cc[s-4][j], cc[s][j]));
                float b = fminf(fminf(hm[s-3][j], hm[s-2][j]), hm[s-1][j]);
                mv[j] = fminf(b, fminf(cc[s-4][j], cc[s][j]));
                float g = fast_sigmoid(Mv[j]) - fast_sigmoid(mv[j]);
                res[j] = (g > 0.5f) ? 1.0f : 0.0f;
                border |= (fabsf(g - 0.5f) < 1e-4f);
            }
            if (__builtin_expect(border, 0)) {
                // exact np-f32 pipeline (fast/exact only disagree in the band)
                #pragma unroll
                for (int j = 0; j < 4; ++j) {
                    float sM = np_sigmoid_f32(Mv[j]);
                    float sm = np_sigmoid_f32(mv[j]);
                    res[j] = ((sM - sm) > 0.5f) ? 1.0f : 0.0f;
                }
            }
            float4 o = make_float4(res[0], res[1], res[2], res[3]);
            *reinterpret_cast<float4*>(obase + (size_t)yo * IMG_W + c) = o;
        }
    }
}

extern "C" void kernel_launch(void* const* d_in, const int* in_sizes, int n_in,
                              void* d_out, int out_size, void* d_ws, size_t ws_size,
                              hipStream_t stream) {
    const float* x = (const float*)d_in[0];
    float* out = (float*)d_out;
    dim3 grid(IMG_W / 256, IMG_H / 64, NIMG);   // 8 x 32 x 8 = 2048 blocks
    dim3 block(64, 4, 1);
    hipLaunchKernelGGL(morph_grad_kernel, grid, block, 0, stream, x, out);
}

// Round 7
// 58.690 us; speedup vs baseline: 1.0975x; 1.0199x over previous
//
#include <hip/hip_runtime.h>
#include <math.h>

#define IMG_H 2048
#define IMG_W 2048
#define NIMG 8

typedef float f32x4 __attribute__((ext_vector_type(4)));

__device__ __forceinline__ float max3f(float a, float b, float c) {
    return fmaxf(fmaxf(a, b), c);
}
__device__ __forceinline__ float min3f(float a, float b, float c) {
    return fminf(fminf(a, b), c);
}

// fast sigmoid: v_exp_f32 + raw v_rcp_f32, ~1e-7 rel error. Only used away
// from the decision boundary (guard band 1e-4); borderline pixels fall
// through to the exact np-f32-pipeline emulation.
__device__ __forceinline__ float fast_sigmoid(float v) {
    float e = __builtin_amdgcn_exp2f(v * -1.44269504088896341f); // exp(-v)
    return __builtin_amdgcn_rcpf(1.0f + e);                      // ~1 ulp rcp
}

// Emulate numpy float32 pipeline: 1.0f / (1.0f + exp_f32(-x)) with a
// correctly-rounded f32 exp (via double), keeping both f32 roundings.
__device__ __forceinline__ float np_sigmoid_f32(float v) {
    float e = (float)exp(-(double)v);   // CR float32 exp
    float d = 1.0f + e;                 // f32 add
    return 1.0f / d;                    // f32 CR div
}

// R2-best structure: each thread 4 cols (float4) x 4 rows; block 64x4 ->
// tile 256x16; 8192 blocks; 40 VGPR; occupancy ~57%. Only deltas vs R2:
// fast sigmoid (rcp instead of IEEE div) and NONTEMPORAL output stores
// (clean A/B: does nt keep the input L3-resident across graph replays?).
__global__ __launch_bounds__(256) void morph_grad_kernel(
    const float* __restrict__ in, float* __restrict__ out) {

    const int tx   = threadIdx.x;                  // 0..63
    const int ty   = threadIdx.y;                  // 0..3
    const int c    = blockIdx.x * 256 + tx * 4;    // output col base (mult of 4)
    const int row0 = blockIdx.y * 16 + ty * 4;     // output row base
    const int img  = blockIdx.z;

    const float* base = in + (size_t)img * (size_t)(IMG_H * IMG_W);

    // hM/hm: horizontal max/min over 5-wide window per row; cc: center value
    float hM[8][4], hm[8][4], cc[8][4];

    const bool hasL = (c != 0);          // c==0 is the only thread missing left halo
    const bool hasR = (c != IMG_W - 4);  // c==2044 is the only one missing right halo

    #pragma unroll
    for (int r = 0; r < 8; ++r) {
        int y = row0 - 2 + r;
        y = y < 0 ? 0 : (y > IMG_H - 1 ? IMG_H - 1 : y);   // clamp == geodesic here
        const float* rp = base + (size_t)y * IMG_W;

        float4 Mv = *reinterpret_cast<const float4*>(rp + c);       // 16B aligned
        float2 Lv, Rv;
        if (hasL) Lv = *reinterpret_cast<const float2*>(rp + c - 2); // 8B aligned
        else      Lv = make_float2(Mv.x, Mv.x);                      // clamp col
        if (hasR) Rv = *reinterpret_cast<const float2*>(rp + c + 4); // 16B aligned
        else      Rv = make_float2(Mv.w, Mv.w);                      // clamp col

        float w[8] = {Lv.x, Lv.y, Mv.x, Mv.y, Mv.z, Mv.w, Rv.x, Rv.y};
        #pragma unroll
        for (int j = 0; j < 4; ++j) {
            float t = max3f(w[j + 1], w[j + 2], w[j + 3]);
            hM[r][j] = max3f(w[j], w[j + 4], t);
            float u = min3f(w[j + 1], w[j + 2], w[j + 3]);
            hm[r][j] = min3f(w[j], w[j + 4], u);
            cc[r][j] = w[j + 2];
        }
    }

    float* obase = out + (size_t)img * (size_t)(IMG_H * IMG_W);

    #pragma unroll
    for (int k = 0; k < 4; ++k) {
        const int yo = row0 + k;
        float rr[4];
        bool border = false;
        float Mvs[4], mvs[4];
        #pragma unroll
        for (int j = 0; j < 4; ++j) {
            // rows yo-1..yo+1 fully covered by hM; rows yo+-2 only center col
            float Mv = max3f(hM[k + 1][j], hM[k + 2][j], hM[k + 3][j]);
            Mv = max3f(Mv, cc[k][j], cc[k + 4][j]);
            float mv = min3f(hm[k + 1][j], hm[k + 2][j], hm[k + 3][j]);
            mv = min3f(mv, cc[k][j], cc[k + 4][j]);
            Mvs[j] = Mv; mvs[j] = mv;

            float g = fast_sigmoid(Mv) - fast_sigmoid(mv);
            rr[j] = (g > 0.5f) ? 1.0f : 0.0f;
            border |= (fabsf(g - 0.5f) < 1e-4f);
        }
        if (__builtin_expect(border, 0)) {
            // borderline: exact emulation of the np float32 pipeline
            #pragma unroll
            for (int j = 0; j < 4; ++j) {
                float sM = np_sigmoid_f32(Mvs[j]);
                float sm = np_sigmoid_f32(mvs[j]);
                rr[j] = ((sM - sm) > 0.5f) ? 1.0f : 0.0f;
            }
        }
        f32x4 o = {rr[0], rr[1], rr[2], rr[3]};
        // nontemporal: output is never re-read; try to avoid L3 allocation so
        // the 128 MiB input stays Infinity-Cache-resident across replays
        __builtin_nontemporal_store(
            o, reinterpret_cast<f32x4*>(obase + (size_t)yo * IMG_W + c));
    }
}

extern "C" void kernel_launch(void* const* d_in, const int* in_sizes, int n_in,
                              void* d_out, int out_size, void* d_ws, size_t ws_size,
                              hipStream_t stream) {
    const float* x = (const float*)d_in[0];
    float* out = (float*)d_out;
    dim3 grid(IMG_W / 256, IMG_H / 16, NIMG);   // 8 x 128 x 8 = 8192 blocks
    dim3 block(64, 4, 1);
    hipLaunchKernelGGL(morph_grad_kernel, grid, block, 0, stream, x, out);
}